// Round 9
// baseline (246.041 us; speedup 1.0000x reference)
//
#include <hip/hip_runtime.h>
#include <hip/hip_bf16.h>
#include <cstdint>

#define T_TOK 2048
#define HID   2048
#define NEXP  64
#define TOPK  6
#define NLOC  8
#define ITR   1408
#define ITR2  2816
#define NSLOT (T_TOK * TOPK)
#define NK1   32   // HID/64
#define NK2   22   // ITR/64

// workspace layout (bytes)
#define OFF_CNT   0
#define OFF_CNT2  32
#define OFF_TOPID 4096
#define OFF_TOPW  (OFF_TOPID + T_TOK * TOPK * 4)
#define OFF_TOK   (OFF_TOPW  + T_TOK * TOPK * 4)
#define OFF_WOF   (OFF_TOK   + NSLOT * 4)
#define OFF_XBF   (OFF_WOF   + NSLOT * 4)
#define OFF_ABUF  (OFF_XBF   + (size_t)T_TOK * HID * 2)

typedef __attribute__((ext_vector_type(4))) float f32x4;
typedef __attribute__((ext_vector_type(8))) short s16x8;
typedef __attribute__((ext_vector_type(4))) short s16x4;

__device__ __forceinline__ short f2bf(float f) {
    union { float f; unsigned u; } v; v.f = f;
    unsigned r = v.u + 0x7FFFu + ((v.u >> 16) & 1u);
    return (short)(r >> 16);
}

// raw barrier: LDS visibility via lgkmcnt(0); vmem prefetch stays in flight
#define BAR() do {                                            \
    asm volatile("s_waitcnt lgkmcnt(0)" ::: "memory");        \
    __builtin_amdgcn_s_barrier();                             \
    asm volatile("" ::: "memory");                            \
} while (0)

// ---------------- prep: zero d_out + counters, cvt x -> bf16 ----------------
__global__ __launch_bounds__(256) void k_prep(const float* __restrict__ x,
                                              short* __restrict__ xbf,
                                              float* __restrict__ out,
                                              int* __restrict__ cnt)
{
    const int r = blockIdx.x;
    const int c = threadIdx.x * 8;
    const float4 a = *(const float4*)&x[(size_t)r * HID + c];
    const float4 b = *(const float4*)&x[(size_t)r * HID + c + 4];
    s16x8 v = { f2bf(a.x), f2bf(a.y), f2bf(a.z), f2bf(a.w),
                f2bf(b.x), f2bf(b.y), f2bf(b.z), f2bf(b.w) };
    *(s16x8*)&xbf[(size_t)r * HID + c] = v;
    float4 z = {0.f, 0.f, 0.f, 0.f};
    *(float4*)&out[(size_t)r * HID + c] = z;
    *(float4*)&out[(size_t)r * HID + c + 4] = z;
    if (r == 0 && threadIdx.x < 16) cnt[threadIdx.x] = 0;
}

// ---------------- routing: softmax + top-6 (stable tie-break) ----------------
__global__ __launch_bounds__(256) void k_route(
    const float* __restrict__ logits, int* __restrict__ cnt,
    int* __restrict__ top_ids, float* __restrict__ top_w)
{
    const int lane = threadIdx.x & 63;
    const int t = blockIdx.x * 4 + (threadIdx.x >> 6);

    float v = logits[t * NEXP + lane];
    float m = v;
    #pragma unroll
    for (int s = 32; s > 0; s >>= 1) m = fmaxf(m, __shfl_xor(m, s));
    float ev = expf(v - m);
    float ssum = ev;
    #pragma unroll
    for (int s = 32; s > 0; s >>= 1) ssum += __shfl_xor(ssum, s);
    float p = ev / ssum;

    float pv = p;
    int ids[TOPK]; float wsel[TOPK]; float wsum = 0.f;
    #pragma unroll
    for (int i = 0; i < TOPK; ++i) {
        float mx = pv;
        #pragma unroll
        for (int s = 32; s > 0; s >>= 1) mx = fmaxf(mx, __shfl_xor(mx, s));
        unsigned long long b = __ballot(pv == mx);
        int idx = (int)__builtin_ctzll(b);
        float w = __shfl(p, idx);
        ids[i] = idx; wsel[i] = w; wsum += w;
        if (lane == idx) pv = -1.0f;
    }
    if (lane < TOPK) {
        top_ids[t * TOPK + lane] = ids[lane];
        top_w[t * TOPK + lane]  = wsel[lane] / wsum;
    }
    if (lane == 0) {
        #pragma unroll
        for (int i = 0; i < TOPK; ++i)
            if ((ids[i] & 7) == 0) atomicAdd(&cnt[ids[i] >> 3], 1);
    }
}

__global__ __launch_bounds__(256) void k_scatter(
    const int* __restrict__ top_ids, const float* __restrict__ top_w,
    const int* __restrict__ cnt, int* __restrict__ cnt2,
    int* __restrict__ tok_of, float* __restrict__ w_of)
{
    const int t = blockIdx.x * 256 + threadIdx.x;
    int offs[NLOC];
    {
        int s = 0;
        #pragma unroll
        for (int i = 0; i < NLOC; ++i) { offs[i] = s; s += cnt[i]; }
    }
    #pragma unroll
    for (int i = 0; i < TOPK; ++i) {
        int id = top_ids[t * TOPK + i];
        if ((id & 7) == 0) {
            int e = id >> 3;
            int s = offs[e] + atomicAdd(&cnt2[e], 1);
            tok_of[s] = t;
            w_of[s]  = top_w[t * TOPK + i];
        }
    }
}

// ------------- GEMM1: M=256 (all tokens once) x N=16 pairs; A direct->reg; W via 8KB LDS -------------
__global__ __launch_bounds__(256, 3) void k_gemm1(
    const short* __restrict__ xbf, const float* __restrict__ w13,
    const float* __restrict__ w13s, const int* __restrict__ cnt,
    const int* __restrict__ tok_of, short* __restrict__ a_buf)
{
    const int b = blockIdx.x;
    const int e = b & 7;
    const int tt = b >> 3;
    int off_e = 0, cntE = 0;
    #pragma unroll
    for (int i = 0; i < NLOC; ++i) { int c = cnt[i]; if (i < e) off_e += c; if (i == e) cntE = c; }
    const int m0 = (tt / 88) * 256;
    if (m0 >= cntE) return;
    const int n0p = (tt % 88) * 16;           // pair-col base in [0, ITR)
    const int base = off_e + m0;
    const int tid = threadIdx.x;
    const int lane = tid & 63;
    const int wm = tid >> 6;                  // wave owns rows wm*64..+63

    __shared__ __align__(16) short Ws[2][32 * 64];   // 8 KB (16 gate + 16 up rows)
    __shared__ int tokp[256];

    tokp[tid] = tok_of[base + ((m0 + tid < cntE) ? tid : 0)];
    __syncthreads();

    // per-lane A fragment pointers (direct global, MFMA layout)
    const short* aptr[4];
    #pragma unroll
    for (int mf = 0; mf < 4; ++mf) {
        const int row = wm * 64 + mf * 16 + (lane & 15);
        aptr[mf] = xbf + (size_t)tokp[row] * HID + (lane >> 4) * 8;
    }
    // W stager: 32 rows (16 gate + 16 up) x 64 cols fp32 per step; 8 floats/thread
    const int wrow = tid >> 3;
    const int wcol = (tid & 7) * 8;
    const float* wptr = w13 + ((size_t)e * ITR2 +
        (wrow < 16 ? n0p + wrow : ITR + n0p + (wrow - 16))) * HID + wcol;
    const int woff = (wrow * 64 + wcol) ^ ((wrow & 7) << 3);
    const int sbase = (e * 22 + (wrow < 16 ? 0 : 11) + (n0p >> 7)) * 16;

    s16x8 raA[8], raB[8];
    float4 rw0A, rw1A, rw0B, rw1B;
    float svA, svB;
    f32x4 acc[2][4] = {};   // [gate/up][mf]

#define LOADW1(kk, R) do { const int kc = min((kk), NK1 - 1);                  \
    rw0##R = *(const float4*)(wptr + kc * 64);                                 \
    rw1##R = *(const float4*)(wptr + kc * 64 + 4);                             \
    sv##R = w13s[sbase + (kc >> 1)]; } while (0)

#define WRITEW1(bf, R) do {                                                    \
    s16x8 v = { f2bf(rw0##R.x * sv##R), f2bf(rw0##R.y * sv##R),                \
                f2bf(rw0##R.z * sv##R), f2bf(rw0##R.w * sv##R),                \
                f2bf(rw1##R.x * sv##R), f2bf(rw1##R.y * sv##R),                \
                f2bf(rw1##R.z * sv##R), f2bf(rw1##R.w * sv##R) };              \
    *(s16x8*)&Ws[bf][woff] = v; } while (0)

#define LOADA1(kk, R) do { _Pragma("unroll")                                   \
    for (int mf = 0; mf < 4; ++mf) {                                           \
        ra##R[mf * 2 + 0] = *(const s16x8*)(aptr[mf] + (kk) * 64);             \
        ra##R[mf * 2 + 1] = *(const s16x8*)(aptr[mf] + (kk) * 64 + 32);        \
    } } while (0)

#define COMP1(bf, R) do { _Pragma("unroll")                                    \
    for (int ks = 0; ks < 2; ++ks) {                                           \
        const int co = ks * 32 + (lane >> 4) * 8;                              \
        _Pragma("unroll")                                                      \
        for (int t = 0; t < 2; ++t) {                                          \
            const int brow = t * 16 + (lane & 15);                             \
            s16x8 bv = *(const s16x8*)&Ws[bf][(brow * 64 + co) ^ ((brow & 7) << 3)]; \
            _Pragma("unroll")                                                  \
            for (int mf = 0; mf < 4; ++mf)                                     \
                acc[t][mf] = __builtin_amdgcn_mfma_f32_16x16x32_bf16(ra##R[mf * 2 + ks], bv, acc[t][mf], 0, 0, 0); \
        } } } while (0)

    LOADA1(0, A); LOADW1(0, A);
    LOADA1(1, B); LOADW1(1, B);
    WRITEW1(0, A);
    LOADW1(2, A);
    __syncthreads();

    for (int k = 0; k < NK1 - 2; k += 2) {
        COMP1(0, A); WRITEW1(1, B); LOADW1(k + 3, B); LOADA1(k + 2, A); BAR();
        COMP1(1, B); WRITEW1(0, A); LOADW1(k + 4, A); LOADA1(k + 3, B); BAR();
    }
    COMP1(0, A); WRITEW1(1, B); BAR();
    COMP1(1, B);

    // epilogue: silu(gate)*up -> a_buf bf16; col = n0p + (lane&15)
    {
        const int col = n0p + (lane & 15);
        #pragma unroll
        for (int mf = 0; mf < 4; ++mf)
        #pragma unroll
        for (int j = 0; j < 4; ++j) {
            const int row = wm * 64 + mf * 16 + (lane >> 4) * 4 + j;
            if (m0 + row < cntE) {
                const float g = acc[0][mf][j], u = acc[1][mf][j];
                const float a = (g / (1.f + __expf(-g))) * u;
                a_buf[(size_t)(base + row) * ITR + col] = f2bf(a);
            }
        }
    }
#undef LOADW1
#undef WRITEW1
#undef LOADA1
#undef COMP1
}

// ------------- GEMM2: M=256 x N=16 out-cols; A direct->reg; W via 4KB LDS -------------
__global__ __launch_bounds__(256, 3) void k_gemm2(
    const short* __restrict__ a_buf, const float* __restrict__ w2,
    const float* __restrict__ w2s, const int* __restrict__ cnt,
    const int* __restrict__ tok_of, const float* __restrict__ w_of,
    float* __restrict__ out)
{
    const int b = blockIdx.x;
    const int e = b & 7;
    const int tt = b >> 3;
    int off_e = 0, cntE = 0;
    #pragma unroll
    for (int i = 0; i < NLOC; ++i) { int c = cnt[i]; if (i < e) off_e += c; if (i == e) cntE = c; }
    const int m0 = (tt / 128) * 256;
    if (m0 >= cntE) return;
    const int n0 = (tt % 128) * 16;
    const int base = off_e + m0;
    const int tid = threadIdx.x;
    const int lane = tid & 63;
    const int wm = tid >> 6;

    __shared__ __align__(16) short Ws[2][16 * 64];   // 4 KB

    const short* aptr[4];
    #pragma unroll
    for (int mf = 0; mf < 4; ++mf) {
        int slot = base + wm * 64 + mf * 16 + (lane & 15);
        if (slot > NSLOT - 1) slot = NSLOT - 1;
        aptr[mf] = a_buf + (size_t)slot * ITR + (lane >> 4) * 8;
    }
    // W stager: 16 rows x 64 cols fp32 per step; 4 floats/thread
    const int wrow = tid >> 4;
    const int wcol = (tid & 15) * 4;
    const float* wptr = w2 + ((size_t)e * HID + n0 + wrow) * ITR + wcol;
    const int woff = (wrow * 64 + wcol) ^ ((wrow & 7) << 3);
    const int sbase = (e * 16 + (n0 >> 7)) * 11;

    s16x8 raA[8], raB[8];
    float4 rw0A, rw0B;
    float svA, svB;
    f32x4 acc[4] = {};   // [mf]

#define LOADW2(kk, R) do { const int kc = min((kk), NK2 - 1);                  \
    rw0##R = *(const float4*)(wptr + kc * 64);                                 \
    sv##R = w2s[sbase + (kc >> 1)]; } while (0)

#define WRITEW2(bf, R) do {                                                    \
    s16x4 v = { f2bf(rw0##R.x * sv##R), f2bf(rw0##R.y * sv##R),                \
                f2bf(rw0##R.z * sv##R), f2bf(rw0##R.w * sv##R) };              \
    *(s16x4*)&Ws[bf][woff] = v; } while (0)

#define LOADA2(kk, R) do { _Pragma("unroll")                                   \
    for (int mf = 0; mf < 4; ++mf) {                                           \
        ra##R[mf * 2 + 0] = *(const s16x8*)(aptr[mf] + (kk) * 64);             \
        ra##R[mf * 2 + 1] = *(const s16x8*)(aptr[mf] + (kk) * 64 + 32);        \
    } } while (0)

#define COMP2(bf, R) do { _Pragma("unroll")                                    \
    for (int ks = 0; ks < 2; ++ks) {                                           \
        const int co = ks * 32 + (lane >> 4) * 8;                              \
        const int brow = lane & 15;                                            \
        s16x8 bv = *(const s16x8*)&Ws[bf][(brow * 64 + co) ^ ((brow & 7) << 3)]; \
        _Pragma("unroll")                                                      \
        for (int mf = 0; mf < 4; ++mf)                                         \
            acc[mf] = __builtin_amdgcn_mfma_f32_16x16x32_bf16(ra##R[mf * 2 + ks], bv, acc[mf], 0, 0, 0); \
    } } while (0)

    LOADA2(0, A); LOADW2(0, A);
    LOADA2(1, B); LOADW2(1, B);
    WRITEW2(0, A);
    LOADW2(2, A);
    __syncthreads();

    for (int k = 0; k < NK2 - 2; k += 2) {
        COMP2(0, A); WRITEW2(1, B); LOADW2(k + 3, B); LOADA2(k + 2, A); BAR();
        COMP2(1, B); WRITEW2(0, A); LOADW2(k + 4, A); LOADA2(k + 3, B); BAR();
    }
    COMP2(0, A); WRITEW2(1, B); BAR();
    COMP2(1, B);

    {
        const int col = n0 + (lane & 15);
        #pragma unroll
        for (int mf = 0; mf < 4; ++mf)
        #pragma unroll
        for (int j = 0; j < 4; ++j) {
            const int row = wm * 64 + mf * 16 + (lane >> 4) * 4 + j;
            if (m0 + row < cntE) {
                const int   t = tok_of[base + row];
                const float w = w_of[base + row];
                atomicAdd(&out[(size_t)t * HID + col], acc[mf][j] * w);
            }
        }
    }
#undef LOADW2
#undef WRITEW2
#undef LOADA2
#undef COMP2
}

extern "C" void kernel_launch(void* const* d_in, const int* in_sizes, int n_in,
                              void* d_out, int out_size, void* d_ws, size_t ws_size,
                              hipStream_t stream)
{
    const float* x      = (const float*)d_in[0];
    const float* logits = (const float*)d_in[1];
    const float* w13    = (const float*)d_in[2];
    const float* w13s   = (const float*)d_in[3];
    const float* w2     = (const float*)d_in[4];
    const float* w2s    = (const float*)d_in[5];
    float* out = (float*)d_out;
    char*  ws  = (char*)d_ws;

    int*   cnt     = (int*)(ws + OFF_CNT);
    int*   cnt2    = (int*)(ws + OFF_CNT2);
    int*   top_ids = (int*)(ws + OFF_TOPID);
    float* top_w   = (float*)(ws + OFF_TOPW);
    int*   tok_of  = (int*)(ws + OFF_TOK);
    float* w_of    = (float*)(ws + OFF_WOF);
    short* xbf     = (short*)(ws + OFF_XBF);
    short* a_buf   = (short*)(ws + OFF_ABUF);

    k_prep   <<<T_TOK,       256, 0, stream>>>(x, xbf, out, cnt);
    k_route  <<<T_TOK / 4,   256, 0, stream>>>(logits, cnt, top_ids, top_w);
    k_scatter<<<T_TOK / 256, 256, 0, stream>>>(top_ids, top_w, cnt, cnt2, tok_of, w_of);
    // m-major flat ids: live blocks (m0 < cntE) are the lowest dispatch ids; expert in low 3 bits
    k_gemm1  <<<88 * 2 * 8,  256, 0, stream>>>(xbf, w13, w13s, cnt, tok_of, a_buf);
    k_gemm2  <<<128 * 2 * 8, 256, 0, stream>>>(a_buf, w2, w2s, cnt, tok_of, w_of, out);
}

// Round 10
// 182.164 us; speedup vs baseline: 1.3507x; 1.3507x over previous
//
#include <hip/hip_runtime.h>
#include <hip/hip_bf16.h>
#include <cstdint>

#define T_TOK 2048
#define HID   2048
#define NEXP  64
#define TOPK  6
#define NLOC  8
#define ITR   1408
#define ITR2  2816
#define NSLOT (T_TOK * TOPK)
#define NK1   32   // HID/64
#define NK2   22   // ITR/64

// workspace layout (bytes)
#define OFF_CNT   0
#define OFF_CNT2  32
#define OFF_TOPID 4096
#define OFF_TOPW  (OFF_TOPID + T_TOK * TOPK * 4)
#define OFF_TOK   (OFF_TOPW  + T_TOK * TOPK * 4)
#define OFF_WOF   (OFF_TOK   + NSLOT * 4)
#define OFF_XBF   (OFF_WOF   + NSLOT * 4)
#define OFF_ABUF  (OFF_XBF   + (size_t)T_TOK * HID * 2)

typedef __attribute__((ext_vector_type(4))) float f32x4;
typedef __attribute__((ext_vector_type(8))) short s16x8;
typedef __attribute__((ext_vector_type(4))) short s16x4;

__device__ __forceinline__ short f2bf(float f) {
    union { float f; unsigned u; } v; v.f = f;
    unsigned r = v.u + 0x7FFFu + ((v.u >> 16) & 1u);
    return (short)(r >> 16);
}

// raw barrier: LDS visibility via lgkmcnt(0); vmem loads stay in flight
#define BAR() do {                                            \
    asm volatile("s_waitcnt lgkmcnt(0)" ::: "memory");        \
    __builtin_amdgcn_s_barrier();                             \
    asm volatile("" ::: "memory");                            \
} while (0)

// ---------------- prep: zero d_out + counters, cvt x -> bf16 ----------------
__global__ __launch_bounds__(256) void k_prep(const float* __restrict__ x,
                                              short* __restrict__ xbf,
                                              float* __restrict__ out,
                                              int* __restrict__ cnt)
{
    const int r = blockIdx.x;
    const int c = threadIdx.x * 8;
    const float4 a = *(const float4*)&x[(size_t)r * HID + c];
    const float4 b = *(const float4*)&x[(size_t)r * HID + c + 4];
    s16x8 v = { f2bf(a.x), f2bf(a.y), f2bf(a.z), f2bf(a.w),
                f2bf(b.x), f2bf(b.y), f2bf(b.z), f2bf(b.w) };
    *(s16x8*)&xbf[(size_t)r * HID + c] = v;
    float4 z = {0.f, 0.f, 0.f, 0.f};
    *(float4*)&out[(size_t)r * HID + c] = z;
    *(float4*)&out[(size_t)r * HID + c + 4] = z;
    if (r == 0 && threadIdx.x < 16) cnt[threadIdx.x] = 0;
}

// ---------------- routing: softmax + top-6 (stable tie-break) ----------------
__global__ __launch_bounds__(256) void k_route(
    const float* __restrict__ logits, int* __restrict__ cnt,
    int* __restrict__ top_ids, float* __restrict__ top_w)
{
    const int lane = threadIdx.x & 63;
    const int t = blockIdx.x * 4 + (threadIdx.x >> 6);

    float v = logits[t * NEXP + lane];
    float m = v;
    #pragma unroll
    for (int s = 32; s > 0; s >>= 1) m = fmaxf(m, __shfl_xor(m, s));
    float ev = expf(v - m);
    float ssum = ev;
    #pragma unroll
    for (int s = 32; s > 0; s >>= 1) ssum += __shfl_xor(ssum, s);
    float p = ev / ssum;

    float pv = p;
    int ids[TOPK]; float wsel[TOPK]; float wsum = 0.f;
    #pragma unroll
    for (int i = 0; i < TOPK; ++i) {
        float mx = pv;
        #pragma unroll
        for (int s = 32; s > 0; s >>= 1) mx = fmaxf(mx, __shfl_xor(mx, s));
        unsigned long long b = __ballot(pv == mx);
        int idx = (int)__builtin_ctzll(b);
        float w = __shfl(p, idx);
        ids[i] = idx; wsel[i] = w; wsum += w;
        if (lane == idx) pv = -1.0f;
    }
    if (lane < TOPK) {
        top_ids[t * TOPK + lane] = ids[lane];
        top_w[t * TOPK + lane]  = wsel[lane] / wsum;
    }
    if (lane == 0) {
        #pragma unroll
        for (int i = 0; i < TOPK; ++i)
            if ((ids[i] & 7) == 0) atomicAdd(&cnt[ids[i] >> 3], 1);
    }
}

__global__ __launch_bounds__(256) void k_scatter(
    const int* __restrict__ top_ids, const float* __restrict__ top_w,
    const int* __restrict__ cnt, int* __restrict__ cnt2,
    int* __restrict__ tok_of, float* __restrict__ w_of)
{
    const int t = blockIdx.x * 256 + threadIdx.x;
    int offs[NLOC];
    {
        int s = 0;
        #pragma unroll
        for (int i = 0; i < NLOC; ++i) { offs[i] = s; s += cnt[i]; }
    }
    #pragma unroll
    for (int i = 0; i < TOPK; ++i) {
        int id = top_ids[t * TOPK + i];
        if ((id & 7) == 0) {
            int e = id >> 3;
            int s = offs[e] + atomicAdd(&cnt2[e], 1);
            tok_of[s] = t;
            w_of[s]  = top_w[t * TOPK + i];
        }
    }
}

// ------- GEMM1: M=256 (weights once) x N=16 pairs; A single-buf LDS 32KB; W dbuf 8KB -------
__global__ __launch_bounds__(256, 3) void k_gemm1(
    const short* __restrict__ xbf, const float* __restrict__ w13,
    const float* __restrict__ w13s, const int* __restrict__ cnt,
    const int* __restrict__ tok_of, short* __restrict__ a_buf)
{
    const int b = blockIdx.x;
    const int e = b & 7;
    const int tt = b >> 3;
    int off_e = 0, cntE = 0;
    #pragma unroll
    for (int i = 0; i < NLOC; ++i) { int c = cnt[i]; if (i < e) off_e += c; if (i == e) cntE = c; }
    const int m0 = (tt / 88) * 256;
    if (m0 >= cntE) return;
    const int n0p = (tt % 88) * 16;           // pair-col base in [0, ITR)
    const int base = off_e + m0;
    const int tid = threadIdx.x;
    const int lane = tid & 63;
    const int wm = tid >> 6;                  // wave owns rows wm*64..+63

    __shared__ __align__(16) short As[256 * 64];     // 32 KB, single-buffered
    __shared__ __align__(16) short Ws[2][32 * 64];   // 8 KB (16 gate + 16 up rows)
    __shared__ int tokp[256];

    tokp[tid] = tok_of[base + ((m0 + tid < cntE) ? tid : 0)];
    __syncthreads();

    // A stager: 8 (row, 16B-chunk) pairs per thread, row-contiguous segments
    unsigned aoffg[8];   // 32-bit global short-offsets from xbf
    int aoffl[8];
    const int acol = (tid & 7) * 8;
    #pragma unroll
    for (int p = 0; p < 8; ++p) {
        const int row = p * 32 + (tid >> 3);
        aoffg[p] = (unsigned)tokp[row] * HID + acol;
        aoffl[p] = (row * 64 + acol) ^ ((row & 7) << 3);
    }
    __syncthreads();

    // W stager: 32 rows (16 gate + 16 up) x 64 cols fp32; 8 floats/thread
    const int wrow = tid >> 3;
    const int wcol = (tid & 7) * 8;
    const float* wptr = w13 + ((size_t)e * ITR2 +
        (wrow < 16 ? n0p + wrow : ITR + n0p + (wrow - 16))) * HID + wcol;
    const int woff = (wrow * 64 + wcol) ^ ((wrow & 7) << 3);
    const int sbase = (e * 22 + (wrow < 16 ? 0 : 11) + (n0p >> 7)) * 16;

    s16x8 ra[8];
    float4 rw0, rw1;
    float sv;
    f32x4 acc[2][4] = {};   // [gate/up][mf]

#define LOADA(kk) do { const int k0 = min((kk), NK1 - 1) * 64;                 \
    _Pragma("unroll")                                                          \
    for (int p = 0; p < 8; ++p) ra[p] = *(const s16x8*)(xbf + aoffg[p] + k0);  \
} while (0)

#define LOADW(kk) do { const int kc = min((kk), NK1 - 1);                      \
    rw0 = *(const float4*)(wptr + kc * 64);                                    \
    rw1 = *(const float4*)(wptr + kc * 64 + 4);                                \
    sv  = w13s[sbase + (kc >> 1)]; } while (0)

#define WRITEA() do { _Pragma("unroll")                                        \
    for (int p = 0; p < 8; ++p) *(s16x8*)&As[aoffl[p]] = ra[p]; } while (0)

#define WRITEW(bf) do {                                                        \
    s16x8 v = { f2bf(rw0.x * sv), f2bf(rw0.y * sv),                            \
                f2bf(rw0.z * sv), f2bf(rw0.w * sv),                            \
                f2bf(rw1.x * sv), f2bf(rw1.y * sv),                            \
                f2bf(rw1.z * sv), f2bf(rw1.w * sv) };                          \
    *(s16x8*)&Ws[bf][woff] = v; } while (0)

#define COMP(bf) do { _Pragma("unroll")                                        \
    for (int ks = 0; ks < 2; ++ks) {                                           \
        const int co = ks * 32 + (lane >> 4) * 8;                              \
        s16x8 af[4];                                                           \
        _Pragma("unroll")                                                      \
        for (int mf = 0; mf < 4; ++mf) {                                       \
            const int row = wm * 64 + mf * 16 + (lane & 15);                   \
            af[mf] = *(const s16x8*)&As[(row * 64 + co) ^ ((row & 7) << 3)];   \
        }                                                                      \
        _Pragma("unroll")                                                      \
        for (int t = 0; t < 2; ++t) {                                          \
            const int brow = t * 16 + (lane & 15);                             \
            s16x8 bv = *(const s16x8*)&Ws[bf][(brow * 64 + co) ^ ((brow & 7) << 3)]; \
            _Pragma("unroll")                                                  \
            for (int mf = 0; mf < 4; ++mf)                                     \
                acc[t][mf] = __builtin_amdgcn_mfma_f32_16x16x32_bf16(af[mf], bv, acc[t][mf], 0, 0, 0); \
        } } } while (0)

    LOADA(0); LOADW(0);
    WRITEA(); WRITEW(0);
    LOADA(1); LOADW(1);
    BAR();
    for (int k = 0; k < NK1; ++k) {
        COMP(k & 1);
        if (k + 1 < NK1) {
            BAR();                       // all waves done reading As(k)
            WRITEA(); WRITEW((k + 1) & 1);
            LOADA(k + 2); LOADW(k + 2);  // stay in flight across BAR
            BAR();
        }
    }

    // epilogue: silu(gate)*up -> a_buf bf16; col = n0p + (lane&15)
    {
        const int col = n0p + (lane & 15);
        #pragma unroll
        for (int mf = 0; mf < 4; ++mf)
        #pragma unroll
        for (int j = 0; j < 4; ++j) {
            const int row = wm * 64 + mf * 16 + (lane >> 4) * 4 + j;
            if (m0 + row < cntE) {
                const float g = acc[0][mf][j], u = acc[1][mf][j];
                const float a = (g / (1.f + __expf(-g))) * u;
                a_buf[(size_t)(base + row) * ITR + col] = f2bf(a);
            }
        }
    }
#undef LOADA
#undef LOADW
#undef WRITEA
#undef WRITEW
#undef COMP
}

// ------- GEMM2: M=256 x N=16 out-cols; A single-buf LDS 32KB; W dbuf 4KB -------
__global__ __launch_bounds__(256, 3) void k_gemm2(
    const short* __restrict__ a_buf, const float* __restrict__ w2,
    const float* __restrict__ w2s, const int* __restrict__ cnt,
    const int* __restrict__ tok_of, const float* __restrict__ w_of,
    float* __restrict__ out)
{
    const int b = blockIdx.x;
    const int e = b & 7;
    const int tt = b >> 3;
    int off_e = 0, cntE = 0;
    #pragma unroll
    for (int i = 0; i < NLOC; ++i) { int c = cnt[i]; if (i < e) off_e += c; if (i == e) cntE = c; }
    const int m0 = (tt / 128) * 256;
    if (m0 >= cntE) return;
    const int n0 = (tt % 128) * 16;
    const int base = off_e + m0;
    const int tid = threadIdx.x;
    const int lane = tid & 63;
    const int wm = tid >> 6;

    __shared__ __align__(16) short As[256 * 64];     // 32 KB, single-buffered
    __shared__ __align__(16) short Ws[2][16 * 64];   // 4 KB

    unsigned aoffg[8];
    int aoffl[8];
    const int acol = (tid & 7) * 8;
    #pragma unroll
    for (int p = 0; p < 8; ++p) {
        const int row = p * 32 + (tid >> 3);
        int slot = base + row; if (slot > NSLOT - 1) slot = NSLOT - 1;
        aoffg[p] = (unsigned)slot * ITR + acol;
        aoffl[p] = (row * 64 + acol) ^ ((row & 7) << 3);
    }
    // W stager: 16 rows x 64 cols fp32; 4 floats/thread
    const int wrow = tid >> 4;
    const int wcol = (tid & 15) * 4;
    const float* wptr = w2 + ((size_t)e * HID + n0 + wrow) * ITR + wcol;
    const int woff = (wrow * 64 + wcol) ^ ((wrow & 7) << 3);
    const int sbase = (e * 16 + (n0 >> 7)) * 11;

    s16x8 ra[8];
    float4 rw0;
    float sv;
    f32x4 acc[4] = {};   // [mf]

#define LOADA(kk) do { const int k0 = min((kk), NK2 - 1) * 64;                 \
    _Pragma("unroll")                                                          \
    for (int p = 0; p < 8; ++p) ra[p] = *(const s16x8*)(a_buf + aoffg[p] + k0);\
} while (0)

#define LOADW(kk) do { const int kc = min((kk), NK2 - 1);                      \
    rw0 = *(const float4*)(wptr + kc * 64);                                    \
    sv  = w2s[sbase + (kc >> 1)]; } while (0)

#define WRITEA() do { _Pragma("unroll")                                        \
    for (int p = 0; p < 8; ++p) *(s16x8*)&As[aoffl[p]] = ra[p]; } while (0)

#define WRITEW(bf) do {                                                        \
    s16x4 v = { f2bf(rw0.x * sv), f2bf(rw0.y * sv),                            \
                f2bf(rw0.z * sv), f2bf(rw0.w * sv) };                          \
    *(s16x4*)&Ws[bf][woff] = v; } while (0)

#define COMP(bf) do { _Pragma("unroll")                                        \
    for (int ks = 0; ks < 2; ++ks) {                                           \
        const int co = ks * 32 + (lane >> 4) * 8;                              \
        const int brow = lane & 15;                                            \
        s16x8 bv = *(const s16x8*)&Ws[bf][(brow * 64 + co) ^ ((brow & 7) << 3)]; \
        _Pragma("unroll")                                                      \
        for (int mf = 0; mf < 4; ++mf) {                                       \
            const int row = wm * 64 + mf * 16 + (lane & 15);                   \
            s16x8 af = *(const s16x8*)&As[(row * 64 + co) ^ ((row & 7) << 3)]; \
            acc[mf] = __builtin_amdgcn_mfma_f32_16x16x32_bf16(af, bv, acc[mf], 0, 0, 0); \
        } } } while (0)

    LOADA(0); LOADW(0);
    WRITEA(); WRITEW(0);
    LOADA(1); LOADW(1);
    BAR();
    for (int k = 0; k < NK2; ++k) {
        COMP(k & 1);
        if (k + 1 < NK2) {
            BAR();
            WRITEA(); WRITEW((k + 1) & 1);
            LOADA(k + 2); LOADW(k + 2);
            BAR();
        }
    }

    {
        const int col = n0 + (lane & 15);
        #pragma unroll
        for (int mf = 0; mf < 4; ++mf)
        #pragma unroll
        for (int j = 0; j < 4; ++j) {
            const int row = wm * 64 + mf * 16 + (lane >> 4) * 4 + j;
            if (m0 + row < cntE) {
                const int   t = tok_of[base + row];
                const float w = w_of[base + row];
                atomicAdd(&out[(size_t)t * HID + col], acc[mf][j] * w);
            }
        }
    }
#undef LOADA
#undef LOADW
#undef WRITEA
#undef WRITEW
#undef COMP
}

extern "C" void kernel_launch(void* const* d_in, const int* in_sizes, int n_in,
                              void* d_out, int out_size, void* d_ws, size_t ws_size,
                              hipStream_t stream)
{
    const float* x      = (const float*)d_in[0];
    const float* logits = (const float*)d_in[1];
    const float* w13    = (const float*)d_in[2];
    const float* w13s   = (const float*)d_in[3];
    const float* w2     = (const float*)d_in[4];
    const float* w2s    = (const float*)d_in[5];
    float* out = (float*)d_out;
    char*  ws  = (char*)d_ws;

    int*   cnt     = (int*)(ws + OFF_CNT);
    int*   cnt2    = (int*)(ws + OFF_CNT2);
    int*   top_ids = (int*)(ws + OFF_TOPID);
    float* top_w   = (float*)(ws + OFF_TOPW);
    int*   tok_of  = (int*)(ws + OFF_TOK);
    float* w_of    = (float*)(ws + OFF_WOF);
    short* xbf     = (short*)(ws + OFF_XBF);
    short* a_buf   = (short*)(ws + OFF_ABUF);

    k_prep   <<<T_TOK,       256, 0, stream>>>(x, xbf, out, cnt);
    k_route  <<<T_TOK / 4,   256, 0, stream>>>(logits, cnt, top_ids, top_w);
    k_scatter<<<T_TOK / 256, 256, 0, stream>>>(top_ids, top_w, cnt, cnt2, tok_of, w_of);
    // live-first flat ids: e in low 3 bits, n next, m slowest (m>0 blocks exit fast)
    k_gemm1  <<<88 * 8 * 8,  256, 0, stream>>>(xbf, w13, w13s, cnt, tok_of, a_buf);
    k_gemm2  <<<128 * 8 * 8, 256, 0, stream>>>(a_buf, w2, w2s, cnt, tok_of, w_of, out);
}